// Round 3
// baseline (444.656 us; speedup 1.0000x reference)
//
#include <hip/hip_runtime.h>
#include <hip/hip_bf16.h>
#include <stdint.h>

#define BATCH 32
#define CIN   256
#define COUT  256
#define FH    64
#define FW    64
#define NK    4
#define CTX   256
#define TEMP  30.0f

typedef __attribute__((ext_vector_type(8))) short bf16x8;
typedef __attribute__((ext_vector_type(4))) float f32x4;

__device__ __forceinline__ unsigned short f2bf(float f) {
    union { float f; uint32_t u; } a; a.f = f;
    uint32_t r = a.u + 0x7fffu + ((a.u >> 16) & 1u);
    return (unsigned short)(r >> 16);
}

// ws layout
#define WMIX_OFF  1024
#define WMIX_BYTES (32u * 9u * 8u * 4u * 256u * 16u)        // 37,748,736
#define XP_OFF    (WMIX_OFF + WMIX_BYTES)
// xp: [b][ch8][q4][y66][col68][r8] bf16  -> 32*8*4*66*68*16 B = 73,383,936

// ---------------- Kernel 1: fused prep (mix+attn | xpad) --------------------
// blocks 0..511: expert-mix (attention fused), blocks 512..3327: xpad.
// One launch: the two independent preprocessing passes overlap on device.
__global__ __launch_bounds__(256, 2) void prep_kernel(
        const float* __restrict__ weight,
        const float* __restrict__ g,
        const float* __restrict__ dw,
        const float* __restrict__ db,
        uint32_t* __restrict__ wmix,
        const float* __restrict__ x,
        uint32_t* __restrict__ xp) {
    __shared__ __align__(16) char LDSU[73856];
    __shared__ float logit_s[8];
    __shared__ float att_s[8];

    const int bid = blockIdx.x;
    const int t   = threadIdx.x;

    if (bid < 512) {
        // ================= mix part =================
        short* S = (short*)LDSU;                 // [nb2][co8][2308]
        const int cog = bid & 31;                // 8 co each
        const int bg  = bid >> 5;                // 2 b each
        const int co0 = cog * 8;
        const int b0  = bg * 2;
        const size_t EST = (size_t)COUT * CIN * 9;

        // fused attention for b0, b0+1
        {
            const int p  = t >> 5;               // pair: nb = p>>2, k = p&3
            const int i0 = t & 31;
            const int nb = p >> 2, k = p & 3;
            const float* gp = g + (size_t)(b0 + nb) * CTX;
            float part = 0.f;
#pragma unroll
            for (int j = 0; j < 8; ++j) {
                const int i = i0 + j * 32;
                part += gp[i] * dw[i * NK + k];
            }
#pragma unroll
            for (int m = 1; m <= 16; m <<= 1) part += __shfl_xor(part, m);
            if (i0 == 0) logit_s[p] = part + db[k];
        }
        __syncthreads();
        if (t < 8) {
            const int nb = t >> 2;
            const float l0 = logit_s[nb * 4 + 0] * (1.f / TEMP);
            const float l1 = logit_s[nb * 4 + 1] * (1.f / TEMP);
            const float l2 = logit_s[nb * 4 + 2] * (1.f / TEMP);
            const float l3 = logit_s[nb * 4 + 3] * (1.f / TEMP);
            const float m  = fmaxf(fmaxf(l0, l1), fmaxf(l2, l3));
            const float e0 = expf(l0 - m), e1 = expf(l1 - m);
            const float e2 = expf(l2 - m), e3 = expf(l3 - m);
            const float s  = e0 + e1 + e2 + e3;
            const int   k  = t & 3;
            const float e  = (k == 0) ? e0 : (k == 1) ? e1 : (k == 2) ? e2 : e3;
            att_s[t] = e / s;
        }
        __syncthreads();

        float a[2][4];
#pragma unroll
        for (int nb = 0; nb < 2; ++nb)
#pragma unroll
            for (int k = 0; k < 4; ++k)
                a[nb][k] = att_s[nb * 4 + k];

        // phase 1: weight -> mixed bf16 in LDS
        const int co_l  = t >> 5;
        const int inner = t & 31;
        const float* wbase = weight + (size_t)(co0 + co_l) * 2304;

#pragma unroll 2
        for (int i = 0; i < 18; ++i) {
            const int e4 = inner + 32 * i;
            float4 w[4];
#pragma unroll
            for (int k = 0; k < 4; ++k)
                w[k] = *(const float4*)(wbase + k * EST + (size_t)e4 * 4);
#pragma unroll
            for (int nb = 0; nb < 2; ++nb) {
                float mx = a[nb][0] * w[0].x + a[nb][1] * w[1].x + a[nb][2] * w[2].x + a[nb][3] * w[3].x;
                float my = a[nb][0] * w[0].y + a[nb][1] * w[1].y + a[nb][2] * w[2].y + a[nb][3] * w[3].y;
                float mz = a[nb][0] * w[0].z + a[nb][1] * w[1].z + a[nb][2] * w[2].z + a[nb][3] * w[3].z;
                float mw = a[nb][0] * w[0].w + a[nb][1] * w[1].w + a[nb][2] * w[2].w + a[nb][3] * w[3].w;
                uint32_t lo = (uint32_t)f2bf(mx) | ((uint32_t)f2bf(my) << 16);
                uint32_t hi = (uint32_t)f2bf(mz) | ((uint32_t)f2bf(mw) << 16);
                uint2* d = (uint2*)(S + ((nb * 8 + co_l) * 2308 + e4 * 4));
                *d = make_uint2(lo, hi);
            }
        }
        __syncthreads();

        // phase 2: LDS -> wmix, coalesced 16B stores
        const int co_w = t & 7;
        const int slot = t >> 3;
#pragma unroll 2
        for (int j = 0; j < 18; ++j) {
            const int GG  = j * 32 + slot;
            const int b_l = (GG >= 288) ? 1 : 0;
            const int rem = GG - b_l * 288;
            const int tap = rem >> 5;
            const int ch  = (rem >> 2) & 7;
            const int q   = rem & 3;
            const short* sp = S + (b_l * 8 + co_w) * 2308;
            const int ebase = (ch * 32 + q * 8) * 9 + tap;
            uint32_t d[4];
#pragma unroll
            for (int rp = 0; rp < 4; ++rp) {
                uint32_t lo = (uint16_t)sp[ebase + (2 * rp) * 9];
                uint32_t hi = (uint16_t)sp[ebase + (2 * rp + 1) * 9];
                d[rp] = lo | (hi << 16);
            }
            uint32_t* dst = wmix +
                ((((size_t)((b0 + b_l) * 9 + tap) * 8 + ch) * 4 + q) * 256 + co0 + co_w) * 4;
            *(uint4*)dst = make_uint4(d[0], d[1], d[2], d[3]);
        }
    } else {
        // ================= xpad part =================
        uint32_t* P = (uint32_t*)LDSU;          // [yy6][q4][col68][rpair4]
        const int idx = bid - 512;
        const int yg  = idx % 11;
        const int rem = idx / 11;
        const int ch  = rem & 7;
        const int b   = rem >> 3;

        for (int i = t; i < 6 * 1088; i += 256) P[i] = 0;
        __syncthreads();

        const int ci_l = t >> 3;
        const int col0 = (t & 7) * 8;
        const int q = ci_l >> 3, r = ci_l & 7;
        unsigned short* Ps = (unsigned short*)P;

#pragma unroll
        for (int yy = 0; yy < 6; ++yy) {
            const int y = yg * 6 + yy;
            if (y >= 1 && y <= 64) {
                const float* xr = x + (((size_t)(b * 256 + ch * 32 + ci_l) * 64) + (y - 1)) * 64 + col0;
                float4 v0 = *(const float4*)xr;
                float4 v1 = *(const float4*)(xr + 4);
                unsigned short bf[8];
                bf[0] = f2bf(v0.x); bf[1] = f2bf(v0.y); bf[2] = f2bf(v0.z); bf[3] = f2bf(v0.w);
                bf[4] = f2bf(v1.x); bf[5] = f2bf(v1.y); bf[6] = f2bf(v1.z); bf[7] = f2bf(v1.w);
#pragma unroll
                for (int j = 0; j < 8; ++j)
                    Ps[yy * 2176 + (q * 68 + (col0 + j + 1)) * 8 + r] = bf[j];
            }
        }
        __syncthreads();

        const int qo = t >> 6, l = t & 63;
#pragma unroll
        for (int yy = 0; yy < 6; ++yy) {
            const int y = yg * 6 + yy;
            uint32_t* base = xp + (((((size_t)(b * 8 + ch) * 4 + qo) * 66) + y) * 68) * 4;
#pragma unroll
            for (int i = 0; i < 4; ++i)
                base[l + i * 64] = P[yy * 1088 + qo * 272 + l + i * 64];
            if (l < 16) base[l + 256] = P[yy * 1088 + qo * 272 + l + 256];
        }
    }
}

// ---------------- Kernel 2: implicit-GEMM conv, LDS-FREE --------------------
// Both operands are pre-swizzled so every MFMA fragment is a contiguous 16 B
// global load (wmix: [tap][ch][q][co][r8]; xp: [ch][q][y][col][r8]).
// Load fragments straight global->VGPR: no LDS, no barriers, no bank
// conflicts; waves fully independent. Working sets per phase (A 24.6 KB,
// B 8.7 KB per block) are L1/L2-resident (FETCH=54 MB << logical 4.8 GB).
// Block 256 thr = 4 indep waves (2co x 2px), wave tile 64co x 64px,
// 4x4 of mfma_f32_16x16x32_bf16. XCD-swizzled grid for L2 locality.
__global__ __launch_bounds__(256, 3) void conv_mfma(
        const char* __restrict__ xp,
        const char* __restrict__ wmix,
        float* __restrict__ out) {
    const int tid  = threadIdx.x;
    const int lane = tid & 63;
    const int wv   = tid >> 6;
    const int wm   = wv & 1;          // co half
    const int wn   = wv >> 1;         // px half == image row offset
    const int l4   = lane >> 4;       // k-quad
    const int m16  = lane & 15;

    // bijective XCD swizzle: 2048 blocks = 8 * 256
    const int bx  = blockIdx.x;
    const int wid = (bx & 7) * 256 + (bx >> 3);
    const int ptile = wid & 31;       // 0..31
    const int coT   = (wid >> 5) & 1; // 0..1
    const int b     = wid >> 6;       // 0..31
    const int y0    = ptile * 2;

    const char* wmix_b = wmix + (size_t)b * 9 * 8 * 4 * 256 * 16;
    const char* xp_b   = xp + (size_t)b * 8 * 4 * 66 * 68 * 16;

    f32x4 acc[4][4];
#pragma unroll
    for (int i = 0; i < 4; ++i)
#pragma unroll
        for (int j = 0; j < 4; ++j)
            acc[i][j] = (f32x4){0.f, 0.f, 0.f, 0.f};

    // lane-invariant A base: + tap*131072 + ch*16384 + sm*256 per fragment
    const char* Abase = wmix_b + (size_t)l4 * 4096
                      + (size_t)(coT * 128 + wm * 64 + m16) * 16;
    const int yout = y0 + wn;         // this wave's output row

#pragma unroll 1
    for (int ch = 0; ch < 8; ++ch) {
#pragma unroll
        for (int dy = 0; dy < 3; ++dy) {
            const char* Ap = Abase + (size_t)ch * 16384 + (size_t)(dy * 3) * 131072;
            const char* Bp = xp_b
                + (((size_t)(ch * 4 + l4)) * 66 + (yout + dy)) * 1088 + m16 * 16;
#pragma unroll
            for (int dx = 0; dx < 3; ++dx) {
                bf16x8 a[4], bb[4];
#pragma unroll
                for (int sm = 0; sm < 4; ++sm)
                    a[sm] = *(const bf16x8*)(Ap + dx * 131072 + sm * 256);
#pragma unroll
                for (int sn = 0; sn < 4; ++sn)
                    bb[sn] = *(const bf16x8*)(Bp + dx * 16 + sn * 256);
                __builtin_amdgcn_s_setprio(1);
#pragma unroll
                for (int sm = 0; sm < 4; ++sm)
#pragma unroll
                    for (int sn = 0; sn < 4; ++sn)
                        acc[sm][sn] = __builtin_amdgcn_mfma_f32_16x16x32_bf16(
                            a[sm], bb[sn], acc[sm][sn], 0, 0, 0);
                __builtin_amdgcn_s_setprio(0);
            }
        }
    }

    // ---- epilogue: D col=lane&15 (px), row=(lane>>4)*4+reg (co) ----
#pragma unroll
    for (int sm = 0; sm < 4; ++sm) {
#pragma unroll
        for (int sn = 0; sn < 4; ++sn) {
#pragma unroll
            for (int r = 0; r < 4; ++r) {
                const int co = coT * 128 + wm * 64 + sm * 16 + l4 * 4 + r;
                const int xx = sn * 16 + m16;
                out[(((size_t)b * COUT + co) * FH + yout) * FW + xx] = acc[sm][sn][r];
            }
        }
    }
}

extern "C" void kernel_launch(void* const* d_in, const int* in_sizes, int n_in,
                              void* d_out, int out_size, void* d_ws, size_t ws_size,
                              hipStream_t stream) {
    const float* x       = (const float*)d_in[0];
    const float* g       = (const float*)d_in[1];
    const float* weight  = (const float*)d_in[2];
    const float* dense_w = (const float*)d_in[3];
    const float* dense_b = (const float*)d_in[4];
    float* out = (float*)d_out;

    uint32_t* wmix = (uint32_t*)((char*)d_ws + WMIX_OFF);
    uint32_t* xp   = (uint32_t*)((char*)d_ws + XP_OFF);

    prep_kernel<<<3328, 256, 0, stream>>>(weight, g, dense_w, dense_b, wmix, x, xp);
    conv_mfma<<<2048, 256, 0, stream>>>((const char*)xp, (const char*)wmix, out);
}